// Round 14
// baseline (239.106 us; speedup 1.0000x reference)
//
#include <hip/hip_runtime.h>
#include <hip/hip_bf16.h>
#include <math.h>

#define NN 100000   // nodes
#define NE 300000   // edges per snapshot
#define NS 5        // snapshots
#define DIN 128
#define HID 256
#define NP 10000    // post nodes
#define NB_N 391    // ceil(NN/256)

#define NBUCK 1024      // bucket count (dst>>7), 782 used
#define NBUCK_USED 782
#define PBLK 64         // partition blocks per snapshot
#define EPB 19          // edges per thread: 64*256*19 >= NE
#define BCAP 2048       // max edges per bucket (mean 384)
#define CAPR 40960      // max compacted rows per snapshot (~33.3K expected)
#define NCPAD 16        // counter stride in ints: one 64B line per counter
#define LDB 136         // W1t LDS row stride in shorts (68 dwords: disjoint 4-bank groups, 2-way free)

typedef short s8v __attribute__((ext_vector_type(8)));   // 8 x bf16
typedef float f4v __attribute__((ext_vector_type(4)));

static __device__ __forceinline__ float bf2f(unsigned short u) {
    union { unsigned int i; float f; } v; v.i = ((unsigned int)u) << 16; return v.f;
}
static __device__ __forceinline__ unsigned short f2bf(float f) {
    union { float f; unsigned int i; } v; v.f = f;
    return (unsigned short)((v.i + 0x7fff + ((v.i >> 16) & 1)) >> 16);   // RNE
}

// ---------------- post marking ----------------

__global__ void setpost_kernel(const int* __restrict__ post, int* __restrict__ isPost,
                               int* __restrict__ needed) {
    int i = blockIdx.x * 256 + threadIdx.x;
    int s = blockIdx.y;
    if (i < NP) {
        int nd = post[i];
        needed[(size_t)s * NN + nd] = 1;
        if (s == 0) isPost[nd] = 1;
    }
}

// ---------------- fused dtype prep: Xb cvt + 3 weight transposes ----------------

__global__ void prep_kernel(const float* __restrict__ X, unsigned short* __restrict__ Xb,
                            const float* __restrict__ W1, unsigned short* __restrict__ W1t,
                            const float* __restrict__ W2, unsigned short* __restrict__ W2t,
                            const float* __restrict__ Wc1, unsigned short* __restrict__ Wc1t) {
    int b = blockIdx.x, t = threadIdx.x;
    if (b < 12500) {                       // Xb: 3.2M float4 quads
        int i = b * 256 + t;
        float4 v = *(const float4*)&X[(size_t)i * 4];
        ushort4 o;
        o.x = f2bf(v.x); o.y = f2bf(v.y); o.z = f2bf(v.z); o.w = f2bf(v.w);
        *(ushort4*)&Xb[(size_t)i * 4] = o;
    } else if (b < 12628) {                // W1t [256][128] <- W1 [128][256]
        int i = (b - 12500) * 256 + t;
        int n = i >> 7, k = i & 127;
        W1t[i] = f2bf(W1[(size_t)k * 256 + n]);
    } else if (b < 12884) {                // W2t [256][256] <- W2 [256][256]
        int i = (b - 12628) * 256 + t;
        int n = i >> 8, k = i & 255;
        W2t[i] = f2bf(W2[(size_t)k * 256 + n]);
    } else {                               // Wc1t [128][256] <- Wc1 [256][128]
        int i = (b - 12884) * 256 + t;
        int n = i >> 8, k = i & 255;
        Wc1t[i] = f2bf(Wc1[(size_t)k * 128 + n]);
    }
}

// ---------------- bucket-partition CSR build (dense writes) ----------------

__global__ void hist_kernel(const int* __restrict__ EI, int* __restrict__ bhist) {
    __shared__ int h[NBUCK];
    int s = blockIdx.y, b = blockIdx.x, t = threadIdx.x;
    for (int q = t; q < NBUCK; q += 256) h[q] = 0;
    __syncthreads();
    const int* dstp = EI + (size_t)s * 2 * NE + NE;
    int e0 = b * (EPB * 256);
    #pragma unroll
    for (int j = 0; j < EPB; j++) {
        int e = e0 + j * 256 + t;
        if (e < NE) atomicAdd(&h[dstp[e] >> 7], 1);
    }
    __syncthreads();
    for (int q = t; q < NBUCK; q += 256)
        if (h[q]) atomicAdd(&bhist[s * NBUCK + q], h[q]);
}

__global__ void bscan_kernel(const int* __restrict__ bhist, int* __restrict__ bbase,
                             int* __restrict__ bcur) {
    __shared__ int sm[NBUCK];
    int s = blockIdx.x, t = threadIdx.x;
    int v = bhist[s * NBUCK + t];
    sm[t] = v;
    __syncthreads();
    for (int d = 1; d < NBUCK; d <<= 1) {
        int x = (t >= d) ? sm[t - d] : 0;
        __syncthreads();
        sm[t] += x;
        __syncthreads();
    }
    int base = sm[t] - v;
    bbase[s * NBUCK + t] = base;
    bcur[s * NBUCK + t] = base;
}

__global__ void part_kernel(const int* __restrict__ EI, int* __restrict__ bcur,
                            int2* __restrict__ pairs) {
    __shared__ int h[NBUCK];
    __shared__ int base[NBUCK];
    int s = blockIdx.y, b = blockIdx.x, t = threadIdx.x;
    for (int q = t; q < NBUCK; q += 256) h[q] = 0;
    __syncthreads();
    const int* srcp = EI + (size_t)s * 2 * NE;
    const int* dstp = srcp + NE;
    int e0 = b * (EPB * 256);
    int rs[EPB], rd[EPB];
    #pragma unroll
    for (int j = 0; j < EPB; j++) {
        int e = e0 + j * 256 + t;
        if (e < NE) {
            rs[j] = srcp[e];
            rd[j] = dstp[e];
            atomicAdd(&h[rd[j] >> 7], 1);
        } else {
            rd[j] = -1; rs[j] = 0;
        }
    }
    __syncthreads();
    for (int q = t; q < NBUCK; q += 256) {
        int c = h[q];
        base[q] = c ? atomicAdd(&bcur[s * NBUCK + q], c) : 0;
    }
    __syncthreads();
    #pragma unroll
    for (int j = 0; j < EPB; j++) {
        if (rd[j] >= 0) {
            int pos = atomicAdd(&base[rd[j] >> 7], 1);
            pairs[(size_t)s * NE + pos] = make_int2(rs[j], rd[j]);
        }
    }
}

__global__ void bucket_csr_kernel(const int2* __restrict__ pairs, const int* __restrict__ bbase,
                                  const int* __restrict__ bhist, const int* __restrict__ isPost,
                                  int* __restrict__ cnt, int* __restrict__ offs,
                                  float* __restrict__ dinv, int* __restrict__ csr,
                                  int* __restrict__ needed) {
    __shared__ int nh[128];
    __shared__ int noff[128];
    __shared__ int sbuf[BCAP];
    int s = blockIdx.y, b = blockIdx.x, t = threadIdx.x;
    int base = bbase[s * NBUCK + b];
    int count = bhist[s * NBUCK + b];
    if (count > BCAP) count = BCAP;   // statistically unreachable
    if (t < 128) nh[t] = 0;
    __syncthreads();
    const int2* pp = pairs + (size_t)s * NE + base;
    for (int e = t; e < count; e += 256)
        atomicAdd(&nh[pp[e].y & 127], 1);
    __syncthreads();
    if (t < 128) noff[t] = nh[t];
    __syncthreads();
    for (int d = 1; d < 128; d <<= 1) {
        int x = 0;
        if (t < 128 && t >= d) x = noff[t - d];
        __syncthreads();
        if (t < 128) noff[t] += x;
        __syncthreads();
    }
    if (t < 128) {
        int excl = noff[t] - nh[t];
        noff[t] = excl;
        int g = b * 128 + t;
        if (g < NN) {
            int c = nh[t];
            cnt[(size_t)s * NN + g]  = c;
            offs[(size_t)s * NN + g] = base + excl;
            dinv[(size_t)s * NN + g] = rsqrtf((float)(c + 1));   // +1 self loop
        }
    }
    __syncthreads();
    for (int e = t; e < count; e += 256) {
        int2 pr = pp[e];
        int pos = atomicAdd(&noff[pr.y & 127], 1);
        sbuf[pos] = pr.x;
        if (isPost[pr.y]) needed[(size_t)s * NN + pr.x] = 1;
    }
    __syncthreads();
    for (int e = t; e < count; e += 256)
        csr[(size_t)s * NE + base + e] = sbuf[e];
}

// ---------------- needed-set compaction, block-aggregated atomic, padded counters ------

__global__ void compact_kernel(const int* __restrict__ needed, int* __restrict__ ncount,
                               int* __restrict__ list, int* __restrict__ inv) {
    __shared__ int wcnt[4];
    __shared__ int gbase;
    int s = blockIdx.y;
    int i = blockIdx.x * 256 + threadIdx.x;
    int wave = threadIdx.x >> 6, lane = threadIdx.x & 63;
    bool pred = (i < NN) && (needed[(size_t)s * NN + i] != 0);
    unsigned long long mask = __ballot(pred);
    int wc = __popcll(mask);
    if (lane == 0) wcnt[wave] = wc;
    __syncthreads();
    if (threadIdx.x == 0) {
        int tot = wcnt[0] + wcnt[1] + wcnt[2] + wcnt[3];
        gbase = tot ? atomicAdd(&ncount[s * NCPAD], tot) : 0;
    }
    __syncthreads();
    if (pred) {
        int wbase = gbase;
        #pragma unroll
        for (int q = 0; q < 4; q++) if (q < wave) wbase += wcnt[q];
        int rank = __popcll(mask & ((1ull << lane) - 1ull));
        int slot = wbase + rank;
        if (slot < CAPR) {
            list[(size_t)s * NN + slot] = i;
            inv[(size_t)s * NN + i] = slot;
        }
    }
}

// ---------------- fused layer-1: ILP-4 register-gather + MFMA, W1t in LDS ------------
// 1024 threads = 16 waves x 16 rows = 256 compacted rows per block.
// Gather batches 4 edges at a time (independent loads -> ~3 latency hops per batch
// instead of a serial per-edge chain); masked remainder points at self row w/ weight 0.

__global__ __launch_bounds__(1024) void agg_mm1_kernel(
        const unsigned short* __restrict__ Xb, const unsigned short* __restrict__ W1t,
        const int* __restrict__ ncount, const float* __restrict__ dinvA,
        const int* __restrict__ offsA, const int* __restrict__ cntA,
        const int* __restrict__ csrA, const int* __restrict__ listA,
        const float* __restrict__ b1, unsigned short* __restrict__ x1cA) {
    int s = blockIdx.y;
    int M = ncount[s * NCPAD];
    if (M > CAPR) M = CAPR;
    if (blockIdx.x * 256 >= M) return;
    const float* dinv = dinvA + (size_t)s * NN;
    const int* offs = offsA + (size_t)s * NN;
    const int* cnt  = cntA + (size_t)s * NN;
    const int* csr  = csrA + (size_t)s * NE;
    const int* list = listA + (size_t)s * NN;
    unsigned short* x1c = x1cA + (size_t)s * CAPR * HID;

    __shared__ unsigned short ldsB[256 * LDB];   // 69.6 KB
    int tid = threadIdx.x;
    for (int q = tid; q < 256 * 16; q += 1024) {
        int n = q >> 4;
        int k8 = (q & 15) * 8;
        *(s8v*)&ldsB[n * LDB + k8] = *(const s8v*)&W1t[n * 128 + k8];
    }
    __syncthreads();

    int wave = tid >> 6, lane = tid & 63, lr = lane & 15, g = lane >> 4;
    int rowbase = blockIdx.x * 256 + wave * 16;
    int arow = rowbase + lr;

    float ga[4][8];
    #pragma unroll
    for (int kk = 0; kk < 4; kk++)
        #pragma unroll
        for (int j = 0; j < 8; j++) ga[kk][j] = 0.f;
    float di = 0.f;

    if (arow < M) {
        int node = list[arow];
        int o = offs[node], c = cnt[node];
        di = dinv[node];
        const unsigned short* rp = Xb + (size_t)node * DIN + g * 8;
        #pragma unroll
        for (int kk = 0; kk < 4; kk++) {
            s8v h = *(const s8v*)(rp + kk * 32);
            #pragma unroll
            for (int j = 0; j < 8; j++) ga[kk][j] = di * bf2f((unsigned short)h[j]);
        }

        // ILP-4 edge batches
        auto acc4 = [&](int sv0, int sv1, int sv2, int sv3,
                        float w0, float w1, float w2, float w3) {
            const unsigned short* p0 = Xb + (size_t)sv0 * DIN + g * 8;
            const unsigned short* p1 = Xb + (size_t)sv1 * DIN + g * 8;
            const unsigned short* p2 = Xb + (size_t)sv2 * DIN + g * 8;
            const unsigned short* p3 = Xb + (size_t)sv3 * DIN + g * 8;
            #pragma unroll
            for (int kk = 0; kk < 4; kk++) {
                s8v h0 = *(const s8v*)(p0 + kk * 32);
                s8v h1 = *(const s8v*)(p1 + kk * 32);
                s8v h2 = *(const s8v*)(p2 + kk * 32);
                s8v h3 = *(const s8v*)(p3 + kk * 32);
                #pragma unroll
                for (int j = 0; j < 8; j++)
                    ga[kk][j] += w0 * bf2f((unsigned short)h0[j])
                               + w1 * bf2f((unsigned short)h1[j])
                               + w2 * bf2f((unsigned short)h2[j])
                               + w3 * bf2f((unsigned short)h3[j]);
            }
        };

        int k = 0;
        for (; k + 4 <= c; k += 4) {
            int sv0 = csr[o + k], sv1 = csr[o + k + 1];
            int sv2 = csr[o + k + 2], sv3 = csr[o + k + 3];
            acc4(sv0, sv1, sv2, sv3, dinv[sv0], dinv[sv1], dinv[sv2], dinv[sv3]);
        }
        int rem = c - k;
        if (rem > 0) {
            int sv0 = csr[o + k];
            int sv1 = (rem > 1) ? csr[o + k + 1] : node;
            int sv2 = (rem > 2) ? csr[o + k + 2] : node;
            acc4(sv0, sv1, sv2, node,
                 dinv[sv0],
                 (rem > 1) ? dinv[sv1] : 0.f,
                 (rem > 2) ? dinv[sv2] : 0.f,
                 0.f);
        }
    }

    f4v acc[16];
    #pragma unroll
    for (int t8 = 0; t8 < 16; t8++) acc[t8] = (f4v){0.f, 0.f, 0.f, 0.f};
    #pragma unroll
    for (int kk = 0; kk < 4; kk++) {
        s8v a;
        #pragma unroll
        for (int j = 0; j < 8; j++) a[j] = (short)f2bf(ga[kk][j]);
        #pragma unroll
        for (int t8 = 0; t8 < 16; t8++) {
            s8v b = *(const s8v*)&ldsB[(t8 * 16 + lr) * LDB + kk * 32 + g * 8];
            acc[t8] = __builtin_amdgcn_mfma_f32_16x16x32_bf16(a, b, acc[t8], 0, 0, 0);
        }
    }

    int orow0 = rowbase + g * 4;
    #pragma unroll
    for (int r = 0; r < 4; r++) {
        int row = orow0 + r;
        float sc = __shfl(di, g * 4 + r, 64);   // di of row rowbase+g*4+r lives in lane lr=g*4+r
        if (row < M) {
            #pragma unroll
            for (int t8 = 0; t8 < 16; t8++) {
                int col = t8 * 16 + lr;
                float v = sc * acc[t8][r] + b1[col];
                x1c[(size_t)row * HID + col] = f2bf(v > 0.f ? v : 0.f);
            }
        }
    }
}

// ---------------- layer-2 pre-aggregation at post slots, 4-edge ILP, batched ---------

__global__ void z2_kernel(const unsigned short* __restrict__ x1cA, const float* __restrict__ dinvA,
                          const int* __restrict__ offsA, const int* __restrict__ cntA,
                          const int* __restrict__ csrA, const int* __restrict__ invA,
                          const int* __restrict__ post, unsigned short* __restrict__ z2bA) {
    int s = blockIdx.y;
    const unsigned short* x1c = x1cA + (size_t)s * CAPR * HID;
    const float* dinv = dinvA + (size_t)s * NN;
    const int* offs = offsA + (size_t)s * NN;
    const int* cnt  = cntA + (size_t)s * NN;
    const int* csr  = csrA + (size_t)s * NE;
    const int* inv  = invA + (size_t)s * NN;
    unsigned short* z2b = z2bA + (size_t)s * NP * HID;

    int wave = threadIdx.x >> 6, lane = threadIdx.x & 63;
    int eg = lane >> 4, el = lane & 15;
    int p = blockIdx.x * 4 + wave;
    if (p >= NP) return;
    int node = post[p];
    int o = offs[node], c = cnt[node];
    float acc0[8] = {0.f, 0.f, 0.f, 0.f, 0.f, 0.f, 0.f, 0.f};
    float acc1[8] = {0.f, 0.f, 0.f, 0.f, 0.f, 0.f, 0.f, 0.f};
    for (int k = eg; k < c; k += 4) {
        int sv = csr[o + k];
        float wgt = dinv[sv];
        int r = inv[sv];
        const unsigned short* rp = &x1c[(size_t)r * HID + el * 16];
        s8v h0 = *(const s8v*)rp;
        s8v h1 = *(const s8v*)(rp + 8);
        #pragma unroll
        for (int j = 0; j < 8; j++) {
            acc0[j] += wgt * bf2f((unsigned short)h0[j]);
            acc1[j] += wgt * bf2f((unsigned short)h1[j]);
        }
    }
    if (eg == 0) {
        float di = dinv[node];
        int r = inv[node];
        const unsigned short* rp = &x1c[(size_t)r * HID + el * 16];
        s8v h0 = *(const s8v*)rp;
        s8v h1 = *(const s8v*)(rp + 8);
        #pragma unroll
        for (int j = 0; j < 8; j++) {
            acc0[j] += di * bf2f((unsigned short)h0[j]);
            acc1[j] += di * bf2f((unsigned short)h1[j]);
        }
    }
    #pragma unroll
    for (int j = 0; j < 8; j++) {
        acc0[j] += __shfl_xor(acc0[j], 16, 64);
        acc0[j] += __shfl_xor(acc0[j], 32, 64);
        acc1[j] += __shfl_xor(acc1[j], 16, 64);
        acc1[j] += __shfl_xor(acc1[j], 32, 64);
    }
    if (eg == 0) {
        s8v o0, o1;
        #pragma unroll
        for (int j = 0; j < 8; j++) {
            o0[j] = (short)f2bf(acc0[j]);
            o1[j] = (short)f2bf(acc1[j]);
        }
        unsigned short* wp = &z2b[(size_t)p * HID + el * 16];
        *(s8v*)wp = o0;
        *(s8v*)(wp + 8) = o1;
    }
}

// ---------------- layer-2 GEMM, batched grid.z = s, 16-wave blocks ----------------
// aggP5[s][row,col] = dinv[nd]*acc + b2[col] + x1c[inv[nd],col]

__global__ __launch_bounds__(1024) void mm2_kernel(
        const unsigned short* __restrict__ z2bA,
        const unsigned short* __restrict__ W2t,
        const float* __restrict__ dinvA,
        const int* __restrict__ post,
        const int* __restrict__ invA,
        const float* __restrict__ b2,
        const unsigned short* __restrict__ x1cA,
        float* __restrict__ aggPA) {
    int s = blockIdx.z;
    const unsigned short* A = z2bA + (size_t)s * NP * HID;
    const float* dinv = dinvA + (size_t)s * NN;
    const int* inv = invA + (size_t)s * NN;
    const unsigned short* x1c = x1cA + (size_t)s * CAPR * HID;
    float* Out = aggPA + (size_t)s * NP * HID;

    __shared__ unsigned short lds[128 * (HID + 8)];   // 67.6 KB
    int tid = threadIdx.x;
    int colbase = blockIdx.y * 128;
    for (int q = tid; q < 128 * 32; q += 1024) {
        int n = q >> 5;
        int k8 = (q & 31) * 8;
        *(s8v*)&lds[n * (HID + 8) + k8] = *(const s8v*)&W2t[(size_t)(colbase + n) * HID + k8];
    }
    __syncthreads();

    int wave = tid >> 6, lane = tid & 63, lr = lane & 15, g = lane >> 4;
    int rowbase = blockIdx.x * 256 + wave * 16;
    int arow = rowbase + lr;

    f4v acc[8];
    #pragma unroll
    for (int t = 0; t < 8; t++) acc[t] = (f4v){0.f, 0.f, 0.f, 0.f};

    #pragma unroll
    for (int kk = 0; kk < HID / 32; kk++) {
        s8v a = (s8v){0, 0, 0, 0, 0, 0, 0, 0};
        if (arow < NP) a = *(const s8v*)&A[(size_t)arow * HID + kk * 32 + g * 8];
        #pragma unroll
        for (int t = 0; t < 8; t++) {
            s8v b = *(const s8v*)&lds[(t * 16 + lr) * (HID + 8) + kk * 32 + g * 8];
            acc[t] = __builtin_amdgcn_mfma_f32_16x16x32_bf16(a, b, acc[t], 0, 0, 0);
        }
    }

    int orow0 = rowbase + g * 4;
    #pragma unroll
    for (int r = 0; r < 4; r++) {
        int row = orow0 + r;
        if (row < NP) {
            int nd = post[row];
            float sc = dinv[nd];
            size_t x1row = (size_t)inv[nd] * HID;
            #pragma unroll
            for (int t = 0; t < 8; t++) {
                int col = colbase + t * 16 + lr;
                Out[(size_t)row * HID + col] =
                    sc * acc[t][r] + b2[col] + bf2f(x1c[x1row + col]);
            }
        }
    }
}

// ---------------- reduce 5 aggP slabs -> bf16 ----------------

__global__ void redcvt_kernel(const float* __restrict__ aggPA, unsigned short* __restrict__ aggPb) {
    int i = blockIdx.x * 256 + threadIdx.x;
    if (i < NP * HID / 4) {
        float4 a = *(const float4*)&aggPA[(size_t)i * 4];
        #pragma unroll
        for (int s = 1; s < NS; s++) {
            float4 b = *(const float4*)&aggPA[(size_t)s * NP * HID + (size_t)i * 4];
            a.x += b.x; a.y += b.y; a.z += b.z; a.w += b.w;
        }
        ushort4 o;
        o.x = f2bf(a.x); o.y = f2bf(a.y); o.z = f2bf(a.z); o.w = f2bf(a.w);
        *(ushort4*)&aggPb[(size_t)i * 4] = o;
    }
}

// ---------------- fused classifier: hid = relu(0.2*aggPb@Wc1+bc1); out = sigmoid(hid.Wc2+bc2)

__global__ __launch_bounds__(256) void mm3f_kernel(
        const unsigned short* __restrict__ A, const unsigned short* __restrict__ Bt,
        const float* __restrict__ bc1, const float* __restrict__ Wc2,
        const float* __restrict__ bc2, float* __restrict__ out) {
    __shared__ float tile[64 * 133];
    __shared__ float wc2s[128];
    int tid = threadIdx.x;
    if (tid < 128) wc2s[tid] = Wc2[tid];
    int wave = tid >> 6, lane = tid & 63, lr = lane & 15, g = lane >> 4;
    int rowbase = blockIdx.x * 64 + wave * 16;
    int arow = rowbase + lr;

    f4v acc[8];
    #pragma unroll
    for (int t = 0; t < 8; t++) acc[t] = (f4v){0.f, 0.f, 0.f, 0.f};

    #pragma unroll
    for (int kk = 0; kk < HID / 32; kk++) {
        s8v a = (s8v){0, 0, 0, 0, 0, 0, 0, 0};
        if (arow < NP) a = *(const s8v*)&A[(size_t)arow * HID + kk * 32 + g * 8];
        #pragma unroll
        for (int t = 0; t < 8; t++) {
            s8v b = *(const s8v*)&Bt[(size_t)(t * 16 + lr) * HID + kk * 32 + g * 8];
            acc[t] = __builtin_amdgcn_mfma_f32_16x16x32_bf16(a, b, acc[t], 0, 0, 0);
        }
    }

    // stage relu(0.2*acc + bc1) into LDS tile [64][133]
    #pragma unroll
    for (int r = 0; r < 4; r++) {
        int lrow = wave * 16 + g * 4 + r;
        #pragma unroll
        for (int t = 0; t < 8; t++) {
            int col = t * 16 + lr;
            float v = 0.2f * acc[t][r] + bc1[col];
            tile[lrow * 133 + col] = v > 0.f ? v : 0.f;
        }
    }
    __syncthreads();

    // reduce: lane -> (row = lane>>2, chunk = lane&3), strided cols chunk+4j
    int lrow = wave * 16 + (lane >> 2);
    int chunk = lane & 3;
    float ssum = 0.f;
    #pragma unroll
    for (int j = 0; j < 32; j++)
        ssum += tile[lrow * 133 + chunk + 4 * j] * wc2s[chunk + 4 * j];
    ssum += __shfl_xor(ssum, 1, 64);
    ssum += __shfl_xor(ssum, 2, 64);
    int p = blockIdx.x * 64 + lrow;
    if (chunk == 0 && p < NP)
        out[p] = 1.f / (1.f + expf(-(ssum + bc2[0])));
}

// ---------------- host ----------------

extern "C" void kernel_launch(void* const* d_in, const int* in_sizes, int n_in,
                              void* d_out, int out_size, void* d_ws, size_t ws_size,
                              hipStream_t stream) {
    const float* X    = (const float*)d_in[0];
    const int*   EI   = (const int*)d_in[1];
    const int*   post = (const int*)d_in[2];
    const float* W1   = (const float*)d_in[3];
    const float* b1   = (const float*)d_in[4];
    const float* W2   = (const float*)d_in[5];
    const float* b2   = (const float*)d_in[6];
    const float* Wc1  = (const float*)d_in[7];
    const float* bc1  = (const float*)d_in[8];
    const float* Wc2  = (const float*)d_in[9];
    const float* bc2  = (const float*)d_in[10];
    float* out = (float*)d_out;

    char* w = (char*)d_ws;
    auto carve = [&](size_t bytes) {
        void* p = (void*)w;
        w += (bytes + 255) & ~(size_t)255;
        return p;
    };
    unsigned short* Xb    = (unsigned short*)carve((size_t)NN * DIN * 2);        // 25.6 MB
    unsigned short* x1c   = (unsigned short*)carve((size_t)NS * CAPR * HID * 2); // 104.9 MB
    unsigned short* z2b5  = (unsigned short*)carve((size_t)NS * NP * HID * 2);   // 25.6 MB
    float* aggP5          = (float*)carve((size_t)NS * NP * HID * 4);            // 51.2 MB
    unsigned short* aggPb = (unsigned short*)carve((size_t)NP * HID * 2);        // 5.1 MB
    unsigned short* W1t   = (unsigned short*)carve((size_t)256 * 128 * 2);
    unsigned short* W2t   = (unsigned short*)carve((size_t)256 * 256 * 2);
    unsigned short* Wc1t  = (unsigned short*)carve((size_t)128 * 256 * 2);
    float* dinv           = (float*)carve((size_t)NS * NN * 4);
    int*   cnt            = (int*)carve((size_t)NS * NN * 4);
    int*   offs           = (int*)carve((size_t)NS * NN * 4);
    int*   needed         = (int*)carve((size_t)NS * NN * 4);
    int*   list           = (int*)carve((size_t)NS * NN * 4);
    int*   inv            = (int*)carve((size_t)NS * NN * 4);
    int*   isPost         = (int*)carve((size_t)NN * 4);
    int*   bhist          = (int*)carve((size_t)NS * NBUCK * 4);
    int*   bbase          = (int*)carve((size_t)NS * NBUCK * 4);
    int*   bcur           = (int*)carve((size_t)NS * NBUCK * 4);
    int*   ncount         = (int*)carve((size_t)NS * NCPAD * 4);   // padded: 1 line per s
    int*   csr            = (int*)carve((size_t)NS * NE * 4);                    // 6 MB
    // pairs aliased into x1c region: lifetimes don't overlap (build before compute)
    int2*  pairs          = (int2*)x1c;                                          // 12 MB < slab

    // ---- zero-init ----
    hipMemsetAsync(needed, 0, (size_t)NS * NN * 4, stream);
    hipMemsetAsync(isPost, 0, (size_t)NN * 4, stream);
    hipMemsetAsync(bhist, 0, (size_t)NS * NBUCK * 4, stream);
    hipMemsetAsync(ncount, 0, (size_t)NS * NCPAD * 4, stream);

    // ---- prep (fused cvt + weight transposes) ----
    prep_kernel<<<13012, 256, 0, stream>>>(X, Xb, W1, W1t, W2, W2t, Wc1, Wc1t);
    setpost_kernel<<<dim3((NP + 255) / 256, NS), 256, 0, stream>>>(post, isPost, needed);

    // ---- bucket-partition CSR build (all snapshots) ----
    hist_kernel<<<dim3(PBLK, NS), 256, 0, stream>>>(EI, bhist);
    bscan_kernel<<<NS, NBUCK, 0, stream>>>(bhist, bbase, bcur);
    part_kernel<<<dim3(PBLK, NS), 256, 0, stream>>>(EI, bcur, pairs);
    bucket_csr_kernel<<<dim3(NBUCK_USED, NS), 256, 0, stream>>>(pairs, bbase, bhist, isPost,
                                                                cnt, offs, dinv, csr, needed);
    compact_kernel<<<dim3(NB_N, NS), 256, 0, stream>>>(needed, ncount, list, inv);

    // ---- batched compute ----
    agg_mm1_kernel<<<dim3((CAPR + 255) / 256, NS), 1024, 0, stream>>>(
        Xb, W1t, ncount, dinv, offs, cnt, csr, list, b1, x1c);
    z2_kernel<<<dim3((NP + 3) / 4, NS), 256, 0, stream>>>(
        x1c, dinv, offs, cnt, csr, inv, post, z2b5);
    mm2_kernel<<<dim3((NP + 255) / 256, 2, NS), 1024, 0, stream>>>(
        z2b5, W2t, dinv, post, inv, b2, x1c, aggP5);

    // ---- classifier ----
    redcvt_kernel<<<(NP * HID / 4 + 255) / 256, 256, 0, stream>>>(aggP5, aggPb);
    mm3f_kernel<<<(NP + 63) / 64, 256, 0, stream>>>(aggPb, Wc1t, bc1, Wc2, bc2, out);
}

// Round 15
// 221.513 us; speedup vs baseline: 1.0794x; 1.0794x over previous
//
#include <hip/hip_runtime.h>
#include <hip/hip_bf16.h>
#include <math.h>

#define NN 100000   // nodes
#define NE 300000   // edges per snapshot
#define NS 5        // snapshots
#define DIN 128
#define HID 256
#define NP 10000    // post nodes
#define NB_N 391    // ceil(NN/256)

#define NBUCK 1024      // bucket count (dst>>7), 782 used
#define NBUCK_USED 782
#define PBLK 64         // partition blocks per snapshot
#define EPB 19          // edges per thread: 64*256*19 >= NE
#define BCAP 2048       // bucket slab capacity (mean 384; overflow statistically unreachable)
#define SLAB (NBUCK * BCAP)   // per-snapshot slab entries for pairs/csr
#define CAPR 40960      // max compacted rows per snapshot (~33.3K expected)
#define NCPAD 16        // counter stride in ints: one 64B line per counter
#define LDB 136         // W1t LDS row stride in shorts (68 dwords: disjoint 4-bank groups, 2-way free)

typedef short s8v __attribute__((ext_vector_type(8)));   // 8 x bf16
typedef float f4v __attribute__((ext_vector_type(4)));

static __device__ __forceinline__ float bf2f(unsigned short u) {
    union { unsigned int i; float f; } v; v.i = ((unsigned int)u) << 16; return v.f;
}
static __device__ __forceinline__ unsigned short f2bf(float f) {
    union { float f; unsigned int i; } v; v.f = f;
    return (unsigned short)((v.i + 0x7fff + ((v.i >> 16) & 1)) >> 16);   // RNE
}

// ---------------- post marking ----------------

__global__ void setpost_kernel(const int* __restrict__ post, int* __restrict__ isPost,
                               int* __restrict__ needed) {
    int i = blockIdx.x * 256 + threadIdx.x;
    int s = blockIdx.y;
    if (i < NP) {
        int nd = post[i];
        needed[(size_t)s * NN + nd] = 1;
        if (s == 0) isPost[nd] = 1;
    }
}

// ---------------- fused dtype prep: Xb cvt + 3 weight transposes ----------------

__global__ void prep_kernel(const float* __restrict__ X, unsigned short* __restrict__ Xb,
                            const float* __restrict__ W1, unsigned short* __restrict__ W1t,
                            const float* __restrict__ W2, unsigned short* __restrict__ W2t,
                            const float* __restrict__ Wc1, unsigned short* __restrict__ Wc1t) {
    int b = blockIdx.x, t = threadIdx.x;
    if (b < 12500) {                       // Xb: 3.2M float4 quads
        int i = b * 256 + t;
        float4 v = *(const float4*)&X[(size_t)i * 4];
        ushort4 o;
        o.x = f2bf(v.x); o.y = f2bf(v.y); o.z = f2bf(v.z); o.w = f2bf(v.w);
        *(ushort4*)&Xb[(size_t)i * 4] = o;
    } else if (b < 12628) {                // W1t [256][128] <- W1 [128][256]
        int i = (b - 12500) * 256 + t;
        int n = i >> 7, k = i & 127;
        W1t[i] = f2bf(W1[(size_t)k * 256 + n]);
    } else if (b < 12884) {                // W2t [256][256] <- W2 [256][256]
        int i = (b - 12628) * 256 + t;
        int n = i >> 8, k = i & 255;
        W2t[i] = f2bf(W2[(size_t)k * 256 + n]);
    } else {                               // Wc1t [128][256] <- Wc1 [256][128]
        int i = (b - 12884) * 256 + t;
        int n = i >> 8, k = i & 255;
        Wc1t[i] = f2bf(Wc1[(size_t)k * 128 + n]);
    }
}

// ---------------- single-pass bucket partition (fixed per-bucket slabs) ----------------

__global__ void binit_kernel(int* __restrict__ bcur) {
    int i = blockIdx.x * 256 + threadIdx.x;
    if (i < NS * NBUCK) bcur[i] = (i % NBUCK) * BCAP;
}

__global__ void part_kernel(const int* __restrict__ EI, int* __restrict__ bcur,
                            int2* __restrict__ pairs) {
    __shared__ int h[NBUCK];
    __shared__ int base[NBUCK];
    int s = blockIdx.y, b = blockIdx.x, t = threadIdx.x;
    for (int q = t; q < NBUCK; q += 256) h[q] = 0;
    __syncthreads();
    const int* srcp = EI + (size_t)s * 2 * NE;
    const int* dstp = srcp + NE;
    int e0 = b * (EPB * 256);
    int rs[EPB], rd[EPB];
    #pragma unroll
    for (int j = 0; j < EPB; j++) {
        int e = e0 + j * 256 + t;
        if (e < NE) {
            rs[j] = srcp[e];
            rd[j] = dstp[e];
            atomicAdd(&h[rd[j] >> 7], 1);
        } else {
            rd[j] = -1; rs[j] = 0;
        }
    }
    __syncthreads();
    for (int q = t; q < NBUCK; q += 256) {
        int c = h[q];
        base[q] = c ? atomicAdd(&bcur[s * NBUCK + q], c) : 0;
    }
    __syncthreads();
    #pragma unroll
    for (int j = 0; j < EPB; j++) {
        if (rd[j] >= 0) {
            int pos = atomicAdd(&base[rd[j] >> 7], 1);
            pairs[(size_t)s * SLAB + pos] = make_int2(rs[j], rd[j]);
        }
    }
}

// per-bucket: node histogram + LDS scan -> cnt/offs/dinv/csr (slab-sparse); mark needed srcs
__global__ void bucket_csr_kernel(const int2* __restrict__ pairs, const int* __restrict__ bcur,
                                  const int* __restrict__ isPost,
                                  int* __restrict__ cnt, int* __restrict__ offs,
                                  float* __restrict__ dinv, int* __restrict__ csr,
                                  int* __restrict__ needed) {
    __shared__ int nh[128];
    __shared__ int noff[128];
    __shared__ int sbuf[BCAP];
    int s = blockIdx.y, b = blockIdx.x, t = threadIdx.x;
    int base = b * BCAP;
    int count = bcur[s * NBUCK + b] - base;
    if (count > BCAP) count = BCAP;   // statistically unreachable
    if (t < 128) nh[t] = 0;
    __syncthreads();
    const int2* pp = pairs + (size_t)s * SLAB + base;
    for (int e = t; e < count; e += 256)
        atomicAdd(&nh[pp[e].y & 127], 1);
    __syncthreads();
    if (t < 128) noff[t] = nh[t];
    __syncthreads();
    for (int d = 1; d < 128; d <<= 1) {
        int x = 0;
        if (t < 128 && t >= d) x = noff[t - d];
        __syncthreads();
        if (t < 128) noff[t] += x;
        __syncthreads();
    }
    if (t < 128) {
        int excl = noff[t] - nh[t];
        noff[t] = excl;
        int g = b * 128 + t;
        if (g < NN) {
            int c = nh[t];
            cnt[(size_t)s * NN + g]  = c;
            offs[(size_t)s * NN + g] = base + excl;
            dinv[(size_t)s * NN + g] = rsqrtf((float)(c + 1));   // +1 self loop
        }
    }
    __syncthreads();
    for (int e = t; e < count; e += 256) {
        int2 pr = pp[e];
        int pos = atomicAdd(&noff[pr.y & 127], 1);
        sbuf[pos] = pr.x;
        if (isPost[pr.y]) needed[(size_t)s * NN + pr.x] = 1;
    }
    __syncthreads();
    for (int e = t; e < count; e += 256)
        csr[(size_t)s * SLAB + base + e] = sbuf[e];
}

// ---------------- needed-set compaction, block-aggregated atomic, padded counters ------

__global__ void compact_kernel(const int* __restrict__ needed, int* __restrict__ ncount,
                               int* __restrict__ list, int* __restrict__ inv) {
    __shared__ int wcnt[4];
    __shared__ int gbase;
    int s = blockIdx.y;
    int i = blockIdx.x * 256 + threadIdx.x;
    int wave = threadIdx.x >> 6, lane = threadIdx.x & 63;
    bool pred = (i < NN) && (needed[(size_t)s * NN + i] != 0);
    unsigned long long mask = __ballot(pred);
    int wc = __popcll(mask);
    if (lane == 0) wcnt[wave] = wc;
    __syncthreads();
    if (threadIdx.x == 0) {
        int tot = wcnt[0] + wcnt[1] + wcnt[2] + wcnt[3];
        gbase = tot ? atomicAdd(&ncount[s * NCPAD], tot) : 0;
    }
    __syncthreads();
    if (pred) {
        int wbase = gbase;
        #pragma unroll
        for (int q = 0; q < 4; q++) if (q < wave) wbase += wcnt[q];
        int rank = __popcll(mask & ((1ull << lane) - 1ull));
        int slot = wbase + rank;
        if (slot < CAPR) {
            list[(size_t)s * NN + slot] = i;
            inv[(size_t)s * NN + i] = slot;
        }
    }
}

// ---------------- fused layer-1: register-gather + MFMA, W1t in LDS (r13 winner) ------

__global__ __launch_bounds__(1024) void agg_mm1_kernel(
        const unsigned short* __restrict__ Xb, const unsigned short* __restrict__ W1t,
        const int* __restrict__ ncount, const float* __restrict__ dinvA,
        const int* __restrict__ offsA, const int* __restrict__ cntA,
        const int* __restrict__ csrA, const int* __restrict__ listA,
        const float* __restrict__ b1, unsigned short* __restrict__ x1cA) {
    int s = blockIdx.y;
    int M = ncount[s * NCPAD];
    if (M > CAPR) M = CAPR;
    if (blockIdx.x * 256 >= M) return;
    const float* dinv = dinvA + (size_t)s * NN;
    const int* offs = offsA + (size_t)s * NN;
    const int* cnt  = cntA + (size_t)s * NN;
    const int* csr  = csrA + (size_t)s * SLAB;
    const int* list = listA + (size_t)s * NN;
    unsigned short* x1c = x1cA + (size_t)s * CAPR * HID;

    __shared__ unsigned short ldsB[256 * LDB];   // 69.6 KB
    int tid = threadIdx.x;
    for (int q = tid; q < 256 * 16; q += 1024) {
        int n = q >> 4;
        int k8 = (q & 15) * 8;
        *(s8v*)&ldsB[n * LDB + k8] = *(const s8v*)&W1t[n * 128 + k8];
    }
    __syncthreads();

    int wave = tid >> 6, lane = tid & 63, lr = lane & 15, g = lane >> 4;
    int rowbase = blockIdx.x * 256 + wave * 16;
    int arow = rowbase + lr;

    float ga[4][8];
    #pragma unroll
    for (int kk = 0; kk < 4; kk++)
        #pragma unroll
        for (int j = 0; j < 8; j++) ga[kk][j] = 0.f;
    float di = 0.f;

    if (arow < M) {
        int node = list[arow];
        int o = offs[node], c = cnt[node];
        di = dinv[node];
        const unsigned short* rp = Xb + (size_t)node * DIN + g * 8;
        #pragma unroll
        for (int kk = 0; kk < 4; kk++) {
            s8v h = *(const s8v*)(rp + kk * 32);
            #pragma unroll
            for (int j = 0; j < 8; j++) ga[kk][j] = di * bf2f((unsigned short)h[j]);
        }
        for (int k = 0; k < c; k++) {
            int sv = csr[o + k];
            float wgt = dinv[sv];
            const unsigned short* sp = Xb + (size_t)sv * DIN + g * 8;
            #pragma unroll
            for (int kk = 0; kk < 4; kk++) {
                s8v h = *(const s8v*)(sp + kk * 32);
                #pragma unroll
                for (int j = 0; j < 8; j++) ga[kk][j] += wgt * bf2f((unsigned short)h[j]);
            }
        }
    }

    f4v acc[16];
    #pragma unroll
    for (int t8 = 0; t8 < 16; t8++) acc[t8] = (f4v){0.f, 0.f, 0.f, 0.f};
    #pragma unroll
    for (int kk = 0; kk < 4; kk++) {
        s8v a;
        #pragma unroll
        for (int j = 0; j < 8; j++) a[j] = (short)f2bf(ga[kk][j]);
        #pragma unroll
        for (int t8 = 0; t8 < 16; t8++) {
            s8v b = *(const s8v*)&ldsB[(t8 * 16 + lr) * LDB + kk * 32 + g * 8];
            acc[t8] = __builtin_amdgcn_mfma_f32_16x16x32_bf16(a, b, acc[t8], 0, 0, 0);
        }
    }

    int orow0 = rowbase + g * 4;
    #pragma unroll
    for (int r = 0; r < 4; r++) {
        int row = orow0 + r;
        float sc = __shfl(di, g * 4 + r, 64);   // di of row rowbase+g*4+r lives in lane lr=g*4+r
        if (row < M) {
            #pragma unroll
            for (int t8 = 0; t8 < 16; t8++) {
                int col = t8 * 16 + lr;
                float v = sc * acc[t8][r] + b1[col];
                x1c[(size_t)row * HID + col] = f2bf(v > 0.f ? v : 0.f);
            }
        }
    }
}

// ---------------- layer-2 pre-aggregation at post slots, 4-edge ILP, batched ---------

__global__ void z2_kernel(const unsigned short* __restrict__ x1cA, const float* __restrict__ dinvA,
                          const int* __restrict__ offsA, const int* __restrict__ cntA,
                          const int* __restrict__ csrA, const int* __restrict__ invA,
                          const int* __restrict__ post, unsigned short* __restrict__ z2bA) {
    int s = blockIdx.y;
    const unsigned short* x1c = x1cA + (size_t)s * CAPR * HID;
    const float* dinv = dinvA + (size_t)s * NN;
    const int* offs = offsA + (size_t)s * NN;
    const int* cnt  = cntA + (size_t)s * NN;
    const int* csr  = csrA + (size_t)s * SLAB;
    const int* inv  = invA + (size_t)s * NN;
    unsigned short* z2b = z2bA + (size_t)s * NP * HID;

    int wave = threadIdx.x >> 6, lane = threadIdx.x & 63;
    int eg = lane >> 4, el = lane & 15;
    int p = blockIdx.x * 4 + wave;
    if (p >= NP) return;
    int node = post[p];
    int o = offs[node], c = cnt[node];
    float acc0[8] = {0.f, 0.f, 0.f, 0.f, 0.f, 0.f, 0.f, 0.f};
    float acc1[8] = {0.f, 0.f, 0.f, 0.f, 0.f, 0.f, 0.f, 0.f};
    for (int k = eg; k < c; k += 4) {
        int sv = csr[o + k];
        float wgt = dinv[sv];
        int r = inv[sv];
        const unsigned short* rp = &x1c[(size_t)r * HID + el * 16];
        s8v h0 = *(const s8v*)rp;
        s8v h1 = *(const s8v*)(rp + 8);
        #pragma unroll
        for (int j = 0; j < 8; j++) {
            acc0[j] += wgt * bf2f((unsigned short)h0[j]);
            acc1[j] += wgt * bf2f((unsigned short)h1[j]);
        }
    }
    if (eg == 0) {
        float di = dinv[node];
        int r = inv[node];
        const unsigned short* rp = &x1c[(size_t)r * HID + el * 16];
        s8v h0 = *(const s8v*)rp;
        s8v h1 = *(const s8v*)(rp + 8);
        #pragma unroll
        for (int j = 0; j < 8; j++) {
            acc0[j] += di * bf2f((unsigned short)h0[j]);
            acc1[j] += di * bf2f((unsigned short)h1[j]);
        }
    }
    #pragma unroll
    for (int j = 0; j < 8; j++) {
        acc0[j] += __shfl_xor(acc0[j], 16, 64);
        acc0[j] += __shfl_xor(acc0[j], 32, 64);
        acc1[j] += __shfl_xor(acc1[j], 16, 64);
        acc1[j] += __shfl_xor(acc1[j], 32, 64);
    }
    if (eg == 0) {
        s8v o0, o1;
        #pragma unroll
        for (int j = 0; j < 8; j++) {
            o0[j] = (short)f2bf(acc0[j]);
            o1[j] = (short)f2bf(acc1[j]);
        }
        unsigned short* wp = &z2b[(size_t)p * HID + el * 16];
        *(s8v*)wp = o0;
        *(s8v*)(wp + 8) = o1;
    }
}

// ---------------- layer-2 GEMM, batched grid.z = s, 16-wave blocks ----------------
// aggP5[s][row,col] = dinv[nd]*acc + b2[col] + x1c[inv[nd],col]

__global__ __launch_bounds__(1024) void mm2_kernel(
        const unsigned short* __restrict__ z2bA,
        const unsigned short* __restrict__ W2t,
        const float* __restrict__ dinvA,
        const int* __restrict__ post,
        const int* __restrict__ invA,
        const float* __restrict__ b2,
        const unsigned short* __restrict__ x1cA,
        float* __restrict__ aggPA) {
    int s = blockIdx.z;
    const unsigned short* A = z2bA + (size_t)s * NP * HID;
    const float* dinv = dinvA + (size_t)s * NN;
    const int* inv = invA + (size_t)s * NN;
    const unsigned short* x1c = x1cA + (size_t)s * CAPR * HID;
    float* Out = aggPA + (size_t)s * NP * HID;

    __shared__ unsigned short lds[128 * (HID + 8)];   // 67.6 KB
    int tid = threadIdx.x;
    int colbase = blockIdx.y * 128;
    for (int q = tid; q < 128 * 32; q += 1024) {
        int n = q >> 5;
        int k8 = (q & 31) * 8;
        *(s8v*)&lds[n * (HID + 8) + k8] = *(const s8v*)&W2t[(size_t)(colbase + n) * HID + k8];
    }
    __syncthreads();

    int wave = tid >> 6, lane = tid & 63, lr = lane & 15, g = lane >> 4;
    int rowbase = blockIdx.x * 256 + wave * 16;
    int arow = rowbase + lr;

    f4v acc[8];
    #pragma unroll
    for (int t = 0; t < 8; t++) acc[t] = (f4v){0.f, 0.f, 0.f, 0.f};

    #pragma unroll
    for (int kk = 0; kk < HID / 32; kk++) {
        s8v a = (s8v){0, 0, 0, 0, 0, 0, 0, 0};
        if (arow < NP) a = *(const s8v*)&A[(size_t)arow * HID + kk * 32 + g * 8];
        #pragma unroll
        for (int t = 0; t < 8; t++) {
            s8v b = *(const s8v*)&lds[(t * 16 + lr) * (HID + 8) + kk * 32 + g * 8];
            acc[t] = __builtin_amdgcn_mfma_f32_16x16x32_bf16(a, b, acc[t], 0, 0, 0);
        }
    }

    int orow0 = rowbase + g * 4;
    #pragma unroll
    for (int r = 0; r < 4; r++) {
        int row = orow0 + r;
        if (row < NP) {
            int nd = post[row];
            float sc = dinv[nd];
            size_t x1row = (size_t)inv[nd] * HID;
            #pragma unroll
            for (int t = 0; t < 8; t++) {
                int col = colbase + t * 16 + lr;
                Out[(size_t)row * HID + col] =
                    sc * acc[t][r] + b2[col] + bf2f(x1c[x1row + col]);
            }
        }
    }
}

// ---------------- fused classifier: sum 5 f32 slabs -> bf16 frag -> GEMM -> sigmoid ----

__global__ __launch_bounds__(256) void mm3f_kernel(
        const float* __restrict__ aggPA, const unsigned short* __restrict__ Bt,
        const float* __restrict__ bc1, const float* __restrict__ Wc2,
        const float* __restrict__ bc2, float* __restrict__ out) {
    __shared__ float tile[64 * 133];
    __shared__ float wc2s[128];
    int tid = threadIdx.x;
    if (tid < 128) wc2s[tid] = Wc2[tid];
    int wave = tid >> 6, lane = tid & 63, lr = lane & 15, g = lane >> 4;
    int rowbase = blockIdx.x * 64 + wave * 16;
    int arow = rowbase + lr;

    f4v acc[8];
    #pragma unroll
    for (int t = 0; t < 8; t++) acc[t] = (f4v){0.f, 0.f, 0.f, 0.f};

    #pragma unroll
    for (int kk = 0; kk < HID / 32; kk++) {
        s8v a = (s8v){0, 0, 0, 0, 0, 0, 0, 0};
        if (arow < NP) {
            float af[8] = {0.f, 0.f, 0.f, 0.f, 0.f, 0.f, 0.f, 0.f};
            #pragma unroll
            for (int s = 0; s < NS; s++) {
                const float* Ap = aggPA + (size_t)s * NP * HID + (size_t)arow * HID + kk * 32 + g * 8;
                float4 v0 = *(const float4*)Ap;
                float4 v1 = *(const float4*)(Ap + 4);
                af[0] += v0.x; af[1] += v0.y; af[2] += v0.z; af[3] += v0.w;
                af[4] += v1.x; af[5] += v1.y; af[6] += v1.z; af[7] += v1.w;
            }
            #pragma unroll
            for (int j = 0; j < 8; j++) a[j] = (short)f2bf(af[j]);
        }
        #pragma unroll
        for (int t = 0; t < 8; t++) {
            s8v b = *(const s8v*)&Bt[(size_t)(t * 16 + lr) * HID + kk * 32 + g * 8];
            acc[t] = __builtin_amdgcn_mfma_f32_16x16x32_bf16(a, b, acc[t], 0, 0, 0);
        }
    }

    // stage relu(0.2*acc + bc1) into LDS tile [64][133]
    #pragma unroll
    for (int r = 0; r < 4; r++) {
        int lrow = wave * 16 + g * 4 + r;
        #pragma unroll
        for (int t = 0; t < 8; t++) {
            int col = t * 16 + lr;
            float v = 0.2f * acc[t][r] + bc1[col];
            tile[lrow * 133 + col] = v > 0.f ? v : 0.f;
        }
    }
    __syncthreads();

    // reduce: lane -> (row = lane>>2, chunk = lane&3), strided cols chunk+4j
    int lrow = wave * 16 + (lane >> 2);
    int chunk = lane & 3;
    float ssum = 0.f;
    #pragma unroll
    for (int j = 0; j < 32; j++)
        ssum += tile[lrow * 133 + chunk + 4 * j] * wc2s[chunk + 4 * j];
    ssum += __shfl_xor(ssum, 1, 64);
    ssum += __shfl_xor(ssum, 2, 64);
    int p = blockIdx.x * 64 + lrow;
    if (chunk == 0 && p < NP)
        out[p] = 1.f / (1.f + expf(-(ssum + bc2[0])));
}

// ---------------- host ----------------

extern "C" void kernel_launch(void* const* d_in, const int* in_sizes, int n_in,
                              void* d_out, int out_size, void* d_ws, size_t ws_size,
                              hipStream_t stream) {
    const float* X    = (const float*)d_in[0];
    const int*   EI   = (const int*)d_in[1];
    const int*   post = (const int*)d_in[2];
    const float* W1   = (const float*)d_in[3];
    const float* b1   = (const float*)d_in[4];
    const float* W2   = (const float*)d_in[5];
    const float* b2   = (const float*)d_in[6];
    const float* Wc1  = (const float*)d_in[7];
    const float* bc1  = (const float*)d_in[8];
    const float* Wc2  = (const float*)d_in[9];
    const float* bc2  = (const float*)d_in[10];
    float* out = (float*)d_out;

    char* w = (char*)d_ws;
    auto carve = [&](size_t bytes) {
        void* p = (void*)w;
        w += (bytes + 255) & ~(size_t)255;
        return p;
    };
    unsigned short* Xb    = (unsigned short*)carve((size_t)NN * DIN * 2);        // 25.6 MB
    unsigned short* x1c   = (unsigned short*)carve((size_t)NS * CAPR * HID * 2); // 104.9 MB
    unsigned short* z2b5  = (unsigned short*)carve((size_t)NS * NP * HID * 2);   // 25.6 MB
    float* aggP5          = (float*)carve((size_t)NS * NP * HID * 4);            // 51.2 MB
    unsigned short* W1t   = (unsigned short*)carve((size_t)256 * 128 * 2);
    unsigned short* W2t   = (unsigned short*)carve((size_t)256 * 256 * 2);
    unsigned short* Wc1t  = (unsigned short*)carve((size_t)128 * 256 * 2);
    float* dinv           = (float*)carve((size_t)NS * NN * 4);
    int*   cnt            = (int*)carve((size_t)NS * NN * 4);
    int*   offs           = (int*)carve((size_t)NS * NN * 4);
    int*   needed         = (int*)carve((size_t)NS * NN * 4);
    int*   list           = (int*)carve((size_t)NS * NN * 4);
    int*   inv            = (int*)carve((size_t)NS * NN * 4);
    int*   isPost         = (int*)carve((size_t)NN * 4);
    int*   bcur           = (int*)carve((size_t)NS * NBUCK * 4);
    int*   ncount         = (int*)carve((size_t)NS * NCPAD * 4);   // padded: 1 line per s
    int*   csr            = (int*)carve((size_t)NS * SLAB * 4);                  // 42 MB
    // pairs aliased into x1c region: lifetimes don't overlap (build before compute)
    int2*  pairs          = (int2*)x1c;                                          // 84 MB < slab

    // ---- zero-init ----
    hipMemsetAsync(needed, 0, (size_t)NS * NN * 4, stream);
    hipMemsetAsync(isPost, 0, (size_t)NN * 4, stream);
    hipMemsetAsync(ncount, 0, (size_t)NS * NCPAD * 4, stream);

    // ---- prep (fused cvt + weight transposes) ----
    prep_kernel<<<13012, 256, 0, stream>>>(X, Xb, W1, W1t, W2, W2t, Wc1, Wc1t);
    setpost_kernel<<<dim3((NP + 255) / 256, NS), 256, 0, stream>>>(post, isPost, needed);

    // ---- single-pass bucket partition + CSR build (all snapshots) ----
    binit_kernel<<<(NS * NBUCK + 255) / 256, 256, 0, stream>>>(bcur);
    part_kernel<<<dim3(PBLK, NS), 256, 0, stream>>>(EI, bcur, pairs);
    bucket_csr_kernel<<<dim3(NBUCK_USED, NS), 256, 0, stream>>>(pairs, bcur, isPost,
                                                                cnt, offs, dinv, csr, needed);
    compact_kernel<<<dim3(NB_N, NS), 256, 0, stream>>>(needed, ncount, list, inv);

    // ---- batched compute ----
    agg_mm1_kernel<<<dim3((CAPR + 255) / 256, NS), 1024, 0, stream>>>(
        Xb, W1t, ncount, dinv, offs, cnt, csr, list, b1, x1c);
    z2_kernel<<<dim3((NP + 3) / 4, NS), 256, 0, stream>>>(
        x1c, dinv, offs, cnt, csr, inv, post, z2b5);
    mm2_kernel<<<dim3((NP + 255) / 256, 2, NS), 1024, 0, stream>>>(
        z2b5, W2t, dinv, post, inv, b2, x1c, aggP5);

    // ---- fused classifier (sums aggP5 slabs inline) ----
    mm3f_kernel<<<(NP + 63) / 64, 256, 0, stream>>>(aggP5, Wc1t, bc1, Wc2, bc2, out);
}

// Round 16
// 216.263 us; speedup vs baseline: 1.1056x; 1.0243x over previous
//
#include <hip/hip_runtime.h>
#include <hip/hip_bf16.h>
#include <math.h>

#define NN 100000   // nodes
#define NE 300000   // edges per snapshot
#define NS 5        // snapshots
#define DIN 128
#define HID 256
#define NP 10000    // post nodes
#define NB_N 391    // ceil(NN/256)

#define NBUCK 1024      // bucket count (dst>>7), 782 used
#define NBUCK_USED 782
#define PBLK 64         // partition blocks per snapshot
#define EPB 19          // edges per thread: 64*256*19 >= NE
#define BCAP 2048       // bucket slab capacity (mean 384; overflow statistically unreachable)
#define SLAB (NBUCK * BCAP)   // per-snapshot slab entries for pairs/csr
#define CAPR 40960      // max compacted rows per snapshot (~33.3K expected)
#define NCPAD 16        // counter stride in ints: one 64B line per counter
#define LDB 136         // W1t LDS row stride in shorts (68 dwords: disjoint 4-bank groups, 2-way free)

typedef short s8v __attribute__((ext_vector_type(8)));   // 8 x bf16
typedef float f4v __attribute__((ext_vector_type(4)));

static __device__ __forceinline__ float bf2f(unsigned short u) {
    union { unsigned int i; float f; } v; v.i = ((unsigned int)u) << 16; return v.f;
}
static __device__ __forceinline__ unsigned short f2bf(float f) {
    union { float f; unsigned int i; } v; v.f = f;
    return (unsigned short)((v.i + 0x7fff + ((v.i >> 16) & 1)) >> 16);   // RNE
}

// ---------------- fused init: zero needed/isPost/ncount + bucket cursor bases ----------

__global__ void init_kernel(int* __restrict__ needed, int* __restrict__ isPost,
                            int* __restrict__ ncount, int* __restrict__ bcur) {
    int i = blockIdx.x * 256 + threadIdx.x;
    if (i < NS * NN) needed[i] = 0;
    if (i < NN) isPost[i] = 0;
    if (i < NS * NCPAD) ncount[i] = 0;
    if (i < NS * NBUCK) bcur[i] = (i % NBUCK) * BCAP;
}

__global__ void setpost_kernel(const int* __restrict__ post, int* __restrict__ isPost) {
    int i = blockIdx.x * 256 + threadIdx.x;
    if (i < NP) isPost[post[i]] = 1;
}

// ---------------- fused dtype prep: Xb cvt + 3 weight transposes ----------------

__global__ void prep_kernel(const float* __restrict__ X, unsigned short* __restrict__ Xb,
                            const float* __restrict__ W1, unsigned short* __restrict__ W1t,
                            const float* __restrict__ W2, unsigned short* __restrict__ W2t,
                            const float* __restrict__ Wc1, unsigned short* __restrict__ Wc1t) {
    int b = blockIdx.x, t = threadIdx.x;
    if (b < 12500) {                       // Xb: 3.2M float4 quads
        int i = b * 256 + t;
        float4 v = *(const float4*)&X[(size_t)i * 4];
        ushort4 o;
        o.x = f2bf(v.x); o.y = f2bf(v.y); o.z = f2bf(v.z); o.w = f2bf(v.w);
        *(ushort4*)&Xb[(size_t)i * 4] = o;
    } else if (b < 12628) {                // W1t [256][128] <- W1 [128][256]
        int i = (b - 12500) * 256 + t;
        int n = i >> 7, k = i & 127;
        W1t[i] = f2bf(W1[(size_t)k * 256 + n]);
    } else if (b < 12884) {                // W2t [256][256] <- W2 [256][256]
        int i = (b - 12628) * 256 + t;
        int n = i >> 8, k = i & 255;
        W2t[i] = f2bf(W2[(size_t)k * 256 + n]);
    } else {                               // Wc1t [128][256] <- Wc1 [256][128]
        int i = (b - 12884) * 256 + t;
        int n = i >> 8, k = i & 255;
        Wc1t[i] = f2bf(Wc1[(size_t)k * 128 + n]);
    }
}

// ---------------- single-pass bucket partition (fixed per-bucket slabs) ----------------

__global__ void part_kernel(const int* __restrict__ EI, int* __restrict__ bcur,
                            int2* __restrict__ pairs) {
    __shared__ int h[NBUCK];
    __shared__ int base[NBUCK];
    int s = blockIdx.y, b = blockIdx.x, t = threadIdx.x;
    for (int q = t; q < NBUCK; q += 256) h[q] = 0;
    __syncthreads();
    const int* srcp = EI + (size_t)s * 2 * NE;
    const int* dstp = srcp + NE;
    int e0 = b * (EPB * 256);
    int rs[EPB], rd[EPB];
    #pragma unroll
    for (int j = 0; j < EPB; j++) {
        int e = e0 + j * 256 + t;
        if (e < NE) {
            rs[j] = srcp[e];
            rd[j] = dstp[e];
            atomicAdd(&h[rd[j] >> 7], 1);
        } else {
            rd[j] = -1; rs[j] = 0;
        }
    }
    __syncthreads();
    for (int q = t; q < NBUCK; q += 256) {
        int c = h[q];
        base[q] = c ? atomicAdd(&bcur[s * NBUCK + q], c) : 0;
    }
    __syncthreads();
    #pragma unroll
    for (int j = 0; j < EPB; j++) {
        if (rd[j] >= 0) {
            int pos = atomicAdd(&base[rd[j] >> 7], 1);
            pairs[(size_t)s * SLAB + pos] = make_int2(rs[j], rd[j]);
        }
    }
}

// per-bucket: node histogram + LDS scan -> cnt/offs/dinv/csr (slab-sparse); mark needed srcs
__global__ void bucket_csr_kernel(const int2* __restrict__ pairs, const int* __restrict__ bcur,
                                  const int* __restrict__ isPost,
                                  int* __restrict__ cnt, int* __restrict__ offs,
                                  float* __restrict__ dinv, int* __restrict__ csr,
                                  int* __restrict__ needed) {
    __shared__ int nh[128];
    __shared__ int noff[128];
    __shared__ int sbuf[BCAP];
    int s = blockIdx.y, b = blockIdx.x, t = threadIdx.x;
    int base = b * BCAP;
    int count = bcur[s * NBUCK + b] - base;
    if (count > BCAP) count = BCAP;   // statistically unreachable
    if (t < 128) nh[t] = 0;
    __syncthreads();
    const int2* pp = pairs + (size_t)s * SLAB + base;
    for (int e = t; e < count; e += 256)
        atomicAdd(&nh[pp[e].y & 127], 1);
    __syncthreads();
    if (t < 128) noff[t] = nh[t];
    __syncthreads();
    for (int d = 1; d < 128; d <<= 1) {
        int x = 0;
        if (t < 128 && t >= d) x = noff[t - d];
        __syncthreads();
        if (t < 128) noff[t] += x;
        __syncthreads();
    }
    if (t < 128) {
        int excl = noff[t] - nh[t];
        noff[t] = excl;
        int g = b * 128 + t;
        if (g < NN) {
            int c = nh[t];
            cnt[(size_t)s * NN + g]  = c;
            offs[(size_t)s * NN + g] = base + excl;
            dinv[(size_t)s * NN + g] = rsqrtf((float)(c + 1));   // +1 self loop
        }
    }
    __syncthreads();
    for (int e = t; e < count; e += 256) {
        int2 pr = pp[e];
        int pos = atomicAdd(&noff[pr.y & 127], 1);
        sbuf[pos] = pr.x;
        if (isPost[pr.y]) needed[(size_t)s * NN + pr.x] = 1;
    }
    __syncthreads();
    for (int e = t; e < count; e += 256)
        csr[(size_t)s * SLAB + base + e] = sbuf[e];
}

// ---------------- needed-set compaction (needed OR isPost), block-aggregated atomic ----

__global__ void compact_kernel(const int* __restrict__ needed, const int* __restrict__ isPost,
                               int* __restrict__ ncount,
                               int* __restrict__ list, int* __restrict__ inv) {
    __shared__ int wcnt[4];
    __shared__ int gbase;
    int s = blockIdx.y;
    int i = blockIdx.x * 256 + threadIdx.x;
    int wave = threadIdx.x >> 6, lane = threadIdx.x & 63;
    bool pred = (i < NN) && ((needed[(size_t)s * NN + i] | isPost[i]) != 0);
    unsigned long long mask = __ballot(pred);
    int wc = __popcll(mask);
    if (lane == 0) wcnt[wave] = wc;
    __syncthreads();
    if (threadIdx.x == 0) {
        int tot = wcnt[0] + wcnt[1] + wcnt[2] + wcnt[3];
        gbase = tot ? atomicAdd(&ncount[s * NCPAD], tot) : 0;
    }
    __syncthreads();
    if (pred) {
        int wbase = gbase;
        #pragma unroll
        for (int q = 0; q < 4; q++) if (q < wave) wbase += wcnt[q];
        int rank = __popcll(mask & ((1ull << lane) - 1ull));
        int slot = wbase + rank;
        if (slot < CAPR) {
            list[(size_t)s * NN + slot] = i;
            inv[(size_t)s * NN + i] = slot;
        }
    }
}

// ---------------- fused layer-1: register-gather + MFMA, W1t in LDS (r13/r15 winner) ---

__global__ __launch_bounds__(1024) void agg_mm1_kernel(
        const unsigned short* __restrict__ Xb, const unsigned short* __restrict__ W1t,
        const int* __restrict__ ncount, const float* __restrict__ dinvA,
        const int* __restrict__ offsA, const int* __restrict__ cntA,
        const int* __restrict__ csrA, const int* __restrict__ listA,
        const float* __restrict__ b1, unsigned short* __restrict__ x1cA) {
    int s = blockIdx.y;
    int M = ncount[s * NCPAD];
    if (M > CAPR) M = CAPR;
    if (blockIdx.x * 256 >= M) return;
    const float* dinv = dinvA + (size_t)s * NN;
    const int* offs = offsA + (size_t)s * NN;
    const int* cnt  = cntA + (size_t)s * NN;
    const int* csr  = csrA + (size_t)s * SLAB;
    const int* list = listA + (size_t)s * NN;
    unsigned short* x1c = x1cA + (size_t)s * CAPR * HID;

    __shared__ unsigned short ldsB[256 * LDB];   // 69.6 KB
    int tid = threadIdx.x;
    for (int q = tid; q < 256 * 16; q += 1024) {
        int n = q >> 4;
        int k8 = (q & 15) * 8;
        *(s8v*)&ldsB[n * LDB + k8] = *(const s8v*)&W1t[n * 128 + k8];
    }
    __syncthreads();

    int wave = tid >> 6, lane = tid & 63, lr = lane & 15, g = lane >> 4;
    int rowbase = blockIdx.x * 256 + wave * 16;
    int arow = rowbase + lr;

    float ga[4][8];
    #pragma unroll
    for (int kk = 0; kk < 4; kk++)
        #pragma unroll
        for (int j = 0; j < 8; j++) ga[kk][j] = 0.f;
    float di = 0.f;

    if (arow < M) {
        int node = list[arow];
        int o = offs[node], c = cnt[node];
        di = dinv[node];
        const unsigned short* rp = Xb + (size_t)node * DIN + g * 8;
        #pragma unroll
        for (int kk = 0; kk < 4; kk++) {
            s8v h = *(const s8v*)(rp + kk * 32);
            #pragma unroll
            for (int j = 0; j < 8; j++) ga[kk][j] = di * bf2f((unsigned short)h[j]);
        }
        for (int k = 0; k < c; k++) {
            int sv = csr[o + k];
            float wgt = dinv[sv];
            const unsigned short* sp = Xb + (size_t)sv * DIN + g * 8;
            #pragma unroll
            for (int kk = 0; kk < 4; kk++) {
                s8v h = *(const s8v*)(sp + kk * 32);
                #pragma unroll
                for (int j = 0; j < 8; j++) ga[kk][j] += wgt * bf2f((unsigned short)h[j]);
            }
        }
    }

    f4v acc[16];
    #pragma unroll
    for (int t8 = 0; t8 < 16; t8++) acc[t8] = (f4v){0.f, 0.f, 0.f, 0.f};
    #pragma unroll
    for (int kk = 0; kk < 4; kk++) {
        s8v a;
        #pragma unroll
        for (int j = 0; j < 8; j++) a[j] = (short)f2bf(ga[kk][j]);
        #pragma unroll
        for (int t8 = 0; t8 < 16; t8++) {
            s8v b = *(const s8v*)&ldsB[(t8 * 16 + lr) * LDB + kk * 32 + g * 8];
            acc[t8] = __builtin_amdgcn_mfma_f32_16x16x32_bf16(a, b, acc[t8], 0, 0, 0);
        }
    }

    int orow0 = rowbase + g * 4;
    #pragma unroll
    for (int r = 0; r < 4; r++) {
        int row = orow0 + r;
        float sc = __shfl(di, g * 4 + r, 64);   // di of row rowbase+g*4+r lives in lane lr=g*4+r
        if (row < M) {
            #pragma unroll
            for (int t8 = 0; t8 < 16; t8++) {
                int col = t8 * 16 + lr;
                float v = sc * acc[t8][r] + b1[col];
                x1c[(size_t)row * HID + col] = f2bf(v > 0.f ? v : 0.f);
            }
        }
    }
}

// ---------------- layer-2 pre-aggregation at post slots, 4-edge ILP, batched ---------

__global__ void z2_kernel(const unsigned short* __restrict__ x1cA, const float* __restrict__ dinvA,
                          const int* __restrict__ offsA, const int* __restrict__ cntA,
                          const int* __restrict__ csrA, const int* __restrict__ invA,
                          const int* __restrict__ post, unsigned short* __restrict__ z2bA) {
    int s = blockIdx.y;
    const unsigned short* x1c = x1cA + (size_t)s * CAPR * HID;
    const float* dinv = dinvA + (size_t)s * NN;
    const int* offs = offsA + (size_t)s * NN;
    const int* cnt  = cntA + (size_t)s * NN;
    const int* csr  = csrA + (size_t)s * SLAB;
    const int* inv  = invA + (size_t)s * NN;
    unsigned short* z2b = z2bA + (size_t)s * NP * HID;

    int wave = threadIdx.x >> 6, lane = threadIdx.x & 63;
    int eg = lane >> 4, el = lane & 15;
    int p = blockIdx.x * 4 + wave;
    if (p >= NP) return;
    int node = post[p];
    int o = offs[node], c = cnt[node];
    float acc0[8] = {0.f, 0.f, 0.f, 0.f, 0.f, 0.f, 0.f, 0.f};
    float acc1[8] = {0.f, 0.f, 0.f, 0.f, 0.f, 0.f, 0.f, 0.f};
    for (int k = eg; k < c; k += 4) {
        int sv = csr[o + k];
        float wgt = dinv[sv];
        int r = inv[sv];
        const unsigned short* rp = &x1c[(size_t)r * HID + el * 16];
        s8v h0 = *(const s8v*)rp;
        s8v h1 = *(const s8v*)(rp + 8);
        #pragma unroll
        for (int j = 0; j < 8; j++) {
            acc0[j] += wgt * bf2f((unsigned short)h0[j]);
            acc1[j] += wgt * bf2f((unsigned short)h1[j]);
        }
    }
    if (eg == 0) {
        float di = dinv[node];
        int r = inv[node];
        const unsigned short* rp = &x1c[(size_t)r * HID + el * 16];
        s8v h0 = *(const s8v*)rp;
        s8v h1 = *(const s8v*)(rp + 8);
        #pragma unroll
        for (int j = 0; j < 8; j++) {
            acc0[j] += di * bf2f((unsigned short)h0[j]);
            acc1[j] += di * bf2f((unsigned short)h1[j]);
        }
    }
    #pragma unroll
    for (int j = 0; j < 8; j++) {
        acc0[j] += __shfl_xor(acc0[j], 16, 64);
        acc0[j] += __shfl_xor(acc0[j], 32, 64);
        acc1[j] += __shfl_xor(acc1[j], 16, 64);
        acc1[j] += __shfl_xor(acc1[j], 32, 64);
    }
    if (eg == 0) {
        s8v o0, o1;
        #pragma unroll
        for (int j = 0; j < 8; j++) {
            o0[j] = (short)f2bf(acc0[j]);
            o1[j] = (short)f2bf(acc1[j]);
        }
        unsigned short* wp = &z2b[(size_t)p * HID + el * 16];
        *(s8v*)wp = o0;
        *(s8v*)(wp + 8) = o1;
    }
}

// ---------------- layer-2 GEMM, batched grid.z = s, 16-wave blocks ----------------
// aggP5[s][row,col] = dinv[nd]*acc + b2[col] + x1c[inv[nd],col]

__global__ __launch_bounds__(1024) void mm2_kernel(
        const unsigned short* __restrict__ z2bA,
        const unsigned short* __restrict__ W2t,
        const float* __restrict__ dinvA,
        const int* __restrict__ post,
        const int* __restrict__ invA,
        const float* __restrict__ b2,
        const unsigned short* __restrict__ x1cA,
        float* __restrict__ aggPA) {
    int s = blockIdx.z;
    const unsigned short* A = z2bA + (size_t)s * NP * HID;
    const float* dinv = dinvA + (size_t)s * NN;
    const int* inv = invA + (size_t)s * NN;
    const unsigned short* x1c = x1cA + (size_t)s * CAPR * HID;
    float* Out = aggPA + (size_t)s * NP * HID;

    __shared__ unsigned short lds[128 * (HID + 8)];   // 67.6 KB
    int tid = threadIdx.x;
    int colbase = blockIdx.y * 128;
    for (int q = tid; q < 128 * 32; q += 1024) {
        int n = q >> 5;
        int k8 = (q & 31) * 8;
        *(s8v*)&lds[n * (HID + 8) + k8] = *(const s8v*)&W2t[(size_t)(colbase + n) * HID + k8];
    }
    __syncthreads();

    int wave = tid >> 6, lane = tid & 63, lr = lane & 15, g = lane >> 4;
    int rowbase = blockIdx.x * 256 + wave * 16;
    int arow = rowbase + lr;

    f4v acc[8];
    #pragma unroll
    for (int t = 0; t < 8; t++) acc[t] = (f4v){0.f, 0.f, 0.f, 0.f};

    #pragma unroll
    for (int kk = 0; kk < HID / 32; kk++) {
        s8v a = (s8v){0, 0, 0, 0, 0, 0, 0, 0};
        if (arow < NP) a = *(const s8v*)&A[(size_t)arow * HID + kk * 32 + g * 8];
        #pragma unroll
        for (int t = 0; t < 8; t++) {
            s8v b = *(const s8v*)&lds[(t * 16 + lr) * (HID + 8) + kk * 32 + g * 8];
            acc[t] = __builtin_amdgcn_mfma_f32_16x16x32_bf16(a, b, acc[t], 0, 0, 0);
        }
    }

    int orow0 = rowbase + g * 4;
    #pragma unroll
    for (int r = 0; r < 4; r++) {
        int row = orow0 + r;
        if (row < NP) {
            int nd = post[row];
            float sc = dinv[nd];
            size_t x1row = (size_t)inv[nd] * HID;
            #pragma unroll
            for (int t = 0; t < 8; t++) {
                int col = colbase + t * 16 + lr;
                Out[(size_t)row * HID + col] =
                    sc * acc[t][r] + b2[col] + bf2f(x1c[x1row + col]);
            }
        }
    }
}

// ---------------- fused classifier: sum 5 f32 slabs -> bf16 frag -> GEMM -> sigmoid ----

__global__ __launch_bounds__(256) void mm3f_kernel(
        const float* __restrict__ aggPA, const unsigned short* __restrict__ Bt,
        const float* __restrict__ bc1, const float* __restrict__ Wc2,
        const float* __restrict__ bc2, float* __restrict__ out) {
    __shared__ float tile[64 * 133];
    __shared__ float wc2s[128];
    int tid = threadIdx.x;
    if (tid < 128) wc2s[tid] = Wc2[tid];
    int wave = tid >> 6, lane = tid & 63, lr = lane & 15, g = lane >> 4;
    int rowbase = blockIdx.x * 64 + wave * 16;
    int arow = rowbase + lr;

    f4v acc[8];
    #pragma unroll
    for (int t = 0; t < 8; t++) acc[t] = (f4v){0.f, 0.f, 0.f, 0.f};

    #pragma unroll
    for (int kk = 0; kk < HID / 32; kk++) {
        s8v a = (s8v){0, 0, 0, 0, 0, 0, 0, 0};
        if (arow < NP) {
            float af[8] = {0.f, 0.f, 0.f, 0.f, 0.f, 0.f, 0.f, 0.f};
            #pragma unroll
            for (int s = 0; s < NS; s++) {
                const float* Ap = aggPA + (size_t)s * NP * HID + (size_t)arow * HID + kk * 32 + g * 8;
                float4 v0 = *(const float4*)Ap;
                float4 v1 = *(const float4*)(Ap + 4);
                af[0] += v0.x; af[1] += v0.y; af[2] += v0.z; af[3] += v0.w;
                af[4] += v1.x; af[5] += v1.y; af[6] += v1.z; af[7] += v1.w;
            }
            #pragma unroll
            for (int j = 0; j < 8; j++) a[j] = (short)f2bf(af[j]);
        }
        #pragma unroll
        for (int t = 0; t < 8; t++) {
            s8v b = *(const s8v*)&Bt[(size_t)(t * 16 + lr) * HID + kk * 32 + g * 8];
            acc[t] = __builtin_amdgcn_mfma_f32_16x16x32_bf16(a, b, acc[t], 0, 0, 0);
        }
    }

    // stage relu(0.2*acc + bc1) into LDS tile [64][133]
    #pragma unroll
    for (int r = 0; r < 4; r++) {
        int lrow = wave * 16 + g * 4 + r;
        #pragma unroll
        for (int t = 0; t < 8; t++) {
            int col = t * 16 + lr;
            float v = 0.2f * acc[t][r] + bc1[col];
            tile[lrow * 133 + col] = v > 0.f ? v : 0.f;
        }
    }
    __syncthreads();

    // reduce: lane -> (row = lane>>2, chunk = lane&3), strided cols chunk+4j
    int lrow = wave * 16 + (lane >> 2);
    int chunk = lane & 3;
    float ssum = 0.f;
    #pragma unroll
    for (int j = 0; j < 32; j++)
        ssum += tile[lrow * 133 + chunk + 4 * j] * wc2s[chunk + 4 * j];
    ssum += __shfl_xor(ssum, 1, 64);
    ssum += __shfl_xor(ssum, 2, 64);
    int p = blockIdx.x * 64 + lrow;
    if (chunk == 0 && p < NP)
        out[p] = 1.f / (1.f + expf(-(ssum + bc2[0])));
}

// ---------------- host ----------------

extern "C" void kernel_launch(void* const* d_in, const int* in_sizes, int n_in,
                              void* d_out, int out_size, void* d_ws, size_t ws_size,
                              hipStream_t stream) {
    const float* X    = (const float*)d_in[0];
    const int*   EI   = (const int*)d_in[1];
    const int*   post = (const int*)d_in[2];
    const float* W1   = (const float*)d_in[3];
    const float* b1   = (const float*)d_in[4];
    const float* W2   = (const float*)d_in[5];
    const float* b2   = (const float*)d_in[6];
    const float* Wc1  = (const float*)d_in[7];
    const float* bc1  = (const float*)d_in[8];
    const float* Wc2  = (const float*)d_in[9];
    const float* bc2  = (const float*)d_in[10];
    float* out = (float*)d_out;

    char* w = (char*)d_ws;
    auto carve = [&](size_t bytes) {
        void* p = (void*)w;
        w += (bytes + 255) & ~(size_t)255;
        return p;
    };
    unsigned short* Xb    = (unsigned short*)carve((size_t)NN * DIN * 2);        // 25.6 MB
    unsigned short* x1c   = (unsigned short*)carve((size_t)NS * CAPR * HID * 2); // 104.9 MB
    unsigned short* z2b5  = (unsigned short*)carve((size_t)NS * NP * HID * 2);   // 25.6 MB
    float* aggP5          = (float*)carve((size_t)NS * NP * HID * 4);            // 51.2 MB
    unsigned short* W1t   = (unsigned short*)carve((size_t)256 * 128 * 2);
    unsigned short* W2t   = (unsigned short*)carve((size_t)256 * 256 * 2);
    unsigned short* Wc1t  = (unsigned short*)carve((size_t)128 * 256 * 2);
    float* dinv           = (float*)carve((size_t)NS * NN * 4);
    int*   cnt            = (int*)carve((size_t)NS * NN * 4);
    int*   offs           = (int*)carve((size_t)NS * NN * 4);
    int*   needed         = (int*)carve((size_t)NS * NN * 4);
    int*   list           = (int*)carve((size_t)NS * NN * 4);
    int*   inv            = (int*)carve((size_t)NS * NN * 4);
    int*   isPost         = (int*)carve((size_t)NN * 4);
    int*   bcur           = (int*)carve((size_t)NS * NBUCK * 4);
    int*   ncount         = (int*)carve((size_t)NS * NCPAD * 4);   // padded: 1 line per s
    int*   csr            = (int*)carve((size_t)NS * SLAB * 4);                  // 42 MB
    // pairs aliased into x1c region: lifetimes don't overlap (build before compute)
    int2*  pairs          = (int2*)x1c;                                          // 84 MB < slab

    // ---- fused init (replaces 3 memsets + binit) ----
    init_kernel<<<(NS * NN + 255) / 256, 256, 0, stream>>>(needed, isPost, ncount, bcur);
    setpost_kernel<<<(NP + 255) / 256, 256, 0, stream>>>(post, isPost);

    // ---- prep (fused cvt + weight transposes) ----
    prep_kernel<<<13012, 256, 0, stream>>>(X, Xb, W1, W1t, W2, W2t, Wc1, Wc1t);

    // ---- single-pass bucket partition + CSR build (all snapshots) ----
    part_kernel<<<dim3(PBLK, NS), 256, 0, stream>>>(EI, bcur, pairs);
    bucket_csr_kernel<<<dim3(NBUCK_USED, NS), 256, 0, stream>>>(pairs, bcur, isPost,
                                                                cnt, offs, dinv, csr, needed);
    compact_kernel<<<dim3(NB_N, NS), 256, 0, stream>>>(needed, isPost, ncount, list, inv);

    // ---- batched compute ----
    agg_mm1_kernel<<<dim3((CAPR + 255) / 256, NS), 1024, 0, stream>>>(
        Xb, W1t, ncount, dinv, offs, cnt, csr, list, b1, x1c);
    z2_kernel<<<dim3((NP + 3) / 4, NS), 256, 0, stream>>>(
        x1c, dinv, offs, cnt, csr, inv, post, z2b5);
    mm2_kernel<<<dim3((NP + 255) / 256, 2, NS), 1024, 0, stream>>>(
        z2b5, W2t, dinv, post, inv, b2, x1c, aggP5);

    // ---- fused classifier (sums aggP5 slabs inline) ----
    mm3f_kernel<<<(NP + 63) / 64, 256, 0, stream>>>(aggP5, Wc1t, bc1, Wc2, bc2, out);
}